// Round 1
// baseline (586.521 us; speedup 1.0000x reference)
//
#include <hip/hip_runtime.h>

// Problem constants (from reference): B=8, T=256, U=64, V=1024
#define BB 8
#define TT 256
#define UU 64
#define VV 1024

// One block, 256 threads (4 waves). Each thread owns 4 of the V=1024 vocab
// entries. Loop over the 8 batch elements; per element do max-reduce, then
// sumexp/dot/sump reduce. Thread 0 accumulates and writes the scalar loss.
__global__ __launch_bounds__(256) void rnnt_align_distill_loss_kernel(
    const float* __restrict__ logits,       // [B,T,U,V]
    const float* __restrict__ soft_labels,  // [B,U,V]
    const int*   __restrict__ aligns,       // [B,U]
    const int*   __restrict__ ylens,        // [B]
    float* __restrict__ out)                // [1]
{
    const int tid  = threadIdx.x;
    const int lane = tid & 63;
    const int wave = tid >> 6;

    __shared__ float red_m[4];
    __shared__ float red_se[4];
    __shared__ float red_dot[4];
    __shared__ float red_sp[4];

    float total = 0.0f;  // only thread 0's copy matters

    for (int b = 0; b < BB; ++b) {
        const int ylen = ylens[b];
        const int u    = ylen - 1;
        const int t    = aligns[b * UU + u];

        const float* sel = logits + ((((size_t)b * TT + t) * UU + u) * VV);
        const float* sp  = soft_labels + (((size_t)b * UU + u) * VV);

        // Register-load 4 elements per thread (coalesced: tid + i*256)
        float x[4], p[4];
        #pragma unroll
        for (int i = 0; i < 4; ++i) {
            const int v = tid + i * 256;
            x[i] = sel[v];
            p[i] = sp[v];
        }

        // ---- max reduce ----
        float m = fmaxf(fmaxf(x[0], x[1]), fmaxf(x[2], x[3]));
        #pragma unroll
        for (int off = 32; off > 0; off >>= 1)
            m = fmaxf(m, __shfl_down(m, off, 64));
        if (lane == 0) red_m[wave] = m;
        __syncthreads();
        m = fmaxf(fmaxf(red_m[0], red_m[1]), fmaxf(red_m[2], red_m[3]));
        __syncthreads();  // red_m reused next b-iteration

        // ---- sumexp, dot(p,x), sum(p) ----
        float se = 0.0f, dot = 0.0f, sump = 0.0f;
        #pragma unroll
        for (int i = 0; i < 4; ++i) {
            se   += expf(x[i] - m);
            dot  += p[i] * x[i];
            sump += p[i];
        }
        #pragma unroll
        for (int off = 32; off > 0; off >>= 1) {
            se   += __shfl_down(se,   off, 64);
            dot  += __shfl_down(dot,  off, 64);
            sump += __shfl_down(sump, off, 64);
        }
        if (lane == 0) { red_se[wave] = se; red_dot[wave] = dot; red_sp[wave] = sump; }
        __syncthreads();

        if (tid == 0) {
            const float se_t   = red_se[0] + red_se[1] + red_se[2] + red_se[3];
            const float dot_t  = red_dot[0] + red_dot[1] + red_dot[2] + red_dot[3];
            const float sump_t = red_sp[0] + red_sp[1] + red_sp[2] + red_sp[3];
            const float lse    = m + logf(se_t);
            // loss_u = sum(p * (x - lse)) / ylen
            const float loss_u = (dot_t - lse * sump_t) / (float)ylen;
            total += loss_u;
        }
        __syncthreads();  // red_* reused next b-iteration
    }

    if (tid == 0) {
        out[0] = -total / (float)BB;  // normalize_batch
    }
}

extern "C" void kernel_launch(void* const* d_in, const int* in_sizes, int n_in,
                              void* d_out, int out_size, void* d_ws, size_t ws_size,
                              hipStream_t stream) {
    const float* logits      = (const float*)d_in[0];
    // d_in[1] = ys (unused by the loss)
    const float* soft_labels = (const float*)d_in[2];
    const int*   aligns      = (const int*)d_in[3];
    // d_in[4] = xlens (unused by the loss)
    const int*   ylens       = (const int*)d_in[5];
    float* out = (float*)d_out;

    rnnt_align_distill_loss_kernel<<<1, 256, 0, stream>>>(
        logits, soft_labels, aligns, ylens, out);
}

// Round 2
// 567.208 us; speedup vs baseline: 1.0341x; 1.0341x over previous
//
#include <hip/hip_runtime.h>

// Problem constants (from reference): B=8, T=256, U=64, V=1024
#define BB 8
#define TT 256
#define UU 64
#define VV 1024

// One block, 512 threads = 8 waves; wave w owns batch element b=w.
// Each lane owns 16 of the V=1024 vocab entries (coalesced lane + i*64).
// Per-wave shuffle reductions (no __syncthreads in the hot path); one
// final cross-wave combine through LDS. Thread 0 writes the scalar loss.
//
// Identity: sum(p * logsoftmax(x)) = dot(p,x) - (max + log(sum exp(x-max))) * sum(p)
__global__ __launch_bounds__(512) void rnnt_align_distill_loss_kernel(
    const float* __restrict__ logits,       // [B,T,U,V]
    const float* __restrict__ soft_labels,  // [B,U,V]
    const int*   __restrict__ aligns,       // [B,U]
    const int*   __restrict__ ylens,        // [B]
    float* __restrict__ out)                // [1]
{
    const int tid  = threadIdx.x;
    const int lane = tid & 63;
    const int b    = tid >> 6;   // wave index == batch element

    __shared__ float red_loss[BB];

    const int ylen = ylens[b];
    const int u    = ylen - 1;
    const int t    = aligns[b * UU + u];

    const float* sel = logits + ((((size_t)b * TT + t) * UU + u) * VV);
    const float* sp  = soft_labels + (((size_t)b * UU + u) * VV);

    // 16 elements per lane, coalesced within the wave.
    float x[16], p[16];
    #pragma unroll
    for (int i = 0; i < 16; ++i) {
        const int v = lane + i * 64;
        x[i] = sel[v];
        p[i] = sp[v];
    }

    // ---- in-wave max reduce ----
    float m = x[0];
    #pragma unroll
    for (int i = 1; i < 16; ++i) m = fmaxf(m, x[i]);
    #pragma unroll
    for (int off = 32; off > 0; off >>= 1)
        m = fmaxf(m, __shfl_down(m, off, 64));
    m = __shfl(m, 0, 64);  // broadcast wave max to all lanes

    // ---- sumexp, dot(p,x), sum(p) ----
    float se = 0.0f, dot = 0.0f, sump = 0.0f;
    #pragma unroll
    for (int i = 0; i < 16; ++i) {
        se   += expf(x[i] - m);
        dot  += p[i] * x[i];
        sump += p[i];
    }
    #pragma unroll
    for (int off = 32; off > 0; off >>= 1) {
        se   += __shfl_down(se,   off, 64);
        dot  += __shfl_down(dot,  off, 64);
        sump += __shfl_down(sump, off, 64);
    }

    if (lane == 0) {
        const float lse    = m + logf(se);
        red_loss[b] = (dot - lse * sump) / (float)ylen;  // loss_u
    }
    __syncthreads();

    if (tid == 0) {
        float total = 0.0f;
        #pragma unroll
        for (int i = 0; i < BB; ++i) total += red_loss[i];
        out[0] = -total / (float)BB;  // normalize_batch
    }
}

extern "C" void kernel_launch(void* const* d_in, const int* in_sizes, int n_in,
                              void* d_out, int out_size, void* d_ws, size_t ws_size,
                              hipStream_t stream) {
    const float* logits      = (const float*)d_in[0];
    // d_in[1] = ys (unused by the loss)
    const float* soft_labels = (const float*)d_in[2];
    const int*   aligns      = (const int*)d_in[3];
    // d_in[4] = xlens (unused by the loss)
    const int*   ylens       = (const int*)d_in[5];
    float* out = (float*)d_out;

    rnnt_align_distill_loss_kernel<<<1, 512, 0, stream>>>(
        logits, soft_labels, aligns, ylens, out);
}